// Round 8
// baseline (75.557 us; speedup 1.0000x reference)
//
#include <hip/hip_runtime.h>

#define BS 256

__device__ __forceinline__ float fast_acos(float x) {
    // Abramowitz & Stegun 4.4.45, branchless; |err| <= ~6.8e-5 rad.
    float ax = fabsf(x);
    float s  = sqrtf(fmaxf(0.f, 1.f - ax));
    float p  = fmaf(ax, fmaf(ax, fmaf(ax, -0.0187293f, 0.0742610f), -0.2121144f), 1.5707288f);
    float r  = s * p;
    return (x >= 0.f) ? r : 3.14159265358979f - r;
}

__device__ __forceinline__ float dir_item(float4 L, float4 O, float4 Tn, bool first) {
    // pred_c = conv_bbox(last + outputs[t])
    float pa = L.x + O.x, pb = L.y + O.y, pc = L.z + O.z, pd = L.w + O.w;
    float Px0 = pa - 0.5f * pc, Py0 = pb - 0.5f * pd, Px1 = pa, Py1 = pb;
    // true_c = conv_bbox(targets[t+1])
    float Tx0 = Tn.x - 0.5f * Tn.z, Ty0 = Tn.y - 0.5f * Tn.w, Tx1 = Tn.x, Ty1 = Tn.y;
    // last_eff: frame 0 -> conv once; frames >=1 -> conv twice (collapsed)
    float Lx1 = L.x - 0.5f * L.z, Ly1 = L.y - 0.5f * L.w;      // conv once
    float Lx0, Ly0;
    if (first) { Lx0 = Lx1; Ly0 = Ly1; Lx1 = L.x; Ly1 = L.y; }
    else       { Lx0 = 0.5f * (L.x - L.z); Ly0 = 0.5f * (L.y - L.w); }

    float lxs[5] = {0.5f * (Lx0 + Lx1), Lx0, Lx0, Lx1, Lx1};
    float lys[5] = {0.5f * (Ly0 + Ly1), Ly0, Ly1, Ly0, Ly1};
    float pxs[5] = {0.5f * (Px0 + Px1), Px0, Px0, Px1, Px1};
    float pys[5] = {0.5f * (Py0 + Py1), Py0, Py1, Py0, Py1};
    float txs[5] = {0.5f * (Tx0 + Tx1), Tx0, Tx0, Tx1, Tx1};
    float tys[5] = {0.5f * (Ty0 + Ty1), Ty0, Ty1, Ty0, Ty1};

    float acc = 0.f;
    #pragma unroll
    for (int k = 0; k < 5; ++k) {
        float pdx = pxs[k] - lxs[k], pdy = pys[k] - lys[k];
        float tdx = txs[k] - lxs[k], tdy = tys[k] - lys[k];
        float p2  = pdx * pdx + pdy * pdy;
        float t2  = tdx * tdx + tdy * tdy;
        float dot = pdx * tdx + pdy * tdy;
        float inv = rsqrtf(p2 * t2);   // ref's +1e-6 eps shifts cos by <=1e-5: within budget
        float cosang = fminf(1.0f, fmaxf(-1.0f, dot * inv));
        acc += fast_acos(cosang);
    }
    return acc;
}

// Each thread owns 4 CONSECUTIVE items: 12 independent dwordx4 loads in flight
// before any compute -> 4x memory-level parallelism vs the grid-stride version.
__global__ void dir_partials(const float* __restrict__ outputs,
                             const float* __restrict__ targets,
                             float* __restrict__ partials,
                             int n, int P) {
    __shared__ float smem[BS / 64];
    long long base = ((long long)blockIdx.x * BS + threadIdx.x) * 4;
    float acc = 0.f;
    if (base + 3 < n) {
        float4 O0 = *reinterpret_cast<const float4*>(outputs + base * 4);
        float4 O1 = *reinterpret_cast<const float4*>(outputs + base * 4 + 4);
        float4 O2 = *reinterpret_cast<const float4*>(outputs + base * 4 + 8);
        float4 O3 = *reinterpret_cast<const float4*>(outputs + base * 4 + 12);
        float4 L0 = *reinterpret_cast<const float4*>(targets + base * 8);
        float4 L1 = *reinterpret_cast<const float4*>(targets + base * 8 + 8);
        float4 L2 = *reinterpret_cast<const float4*>(targets + base * 8 + 16);
        float4 L3 = *reinterpret_cast<const float4*>(targets + base * 8 + 24);
        float4 T0 = *reinterpret_cast<const float4*>(targets + (base + P) * 8);
        float4 T1 = *reinterpret_cast<const float4*>(targets + (base + P) * 8 + 8);
        float4 T2 = *reinterpret_cast<const float4*>(targets + (base + P) * 8 + 16);
        float4 T3 = *reinterpret_cast<const float4*>(targets + (base + P) * 8 + 24);
        acc  = dir_item(L0, O0, T0, (base + 0) < P);
        acc += dir_item(L1, O1, T1, (base + 1) < P);
        acc += dir_item(L2, O2, T2, (base + 2) < P);
        acc += dir_item(L3, O3, T3, (base + 3) < P);
    } else {
        for (long long i = base; i < n; ++i) {
            float4 O = *reinterpret_cast<const float4*>(outputs + i * 4);
            float4 L = *reinterpret_cast<const float4*>(targets + i * 8);
            float4 Tn = *reinterpret_cast<const float4*>(targets + (i + P) * 8);
            acc += dir_item(L, O, Tn, i < P);
        }
    }
    #pragma unroll
    for (int off = 32; off > 0; off >>= 1) acc += __shfl_down(acc, off, 64);
    int lane = threadIdx.x & 63, w = threadIdx.x >> 6;
    if (lane == 0) smem[w] = acc;
    __syncthreads();
    if (threadIdx.x == 0) {
        float r = 0.f;
        #pragma unroll
        for (int i = 0; i < BS / 64; ++i) r += smem[i];
        partials[blockIdx.x] = r;
    }
}

__global__ void out_kernel(const float* __restrict__ outputs,
                           const float* __restrict__ targets,
                           const float* __restrict__ partials, int nb,
                           float* __restrict__ out,
                           int n, int P, float inv_p) {
    // Every block redundantly reduces the partials (L2-resident) to the
    // direction-loss scalar — no separate finalize launch.
    __shared__ double dsm[BS / 64];
    __shared__ float c_sh;
    double dacc = 0.0;
    for (int i = threadIdx.x; i < nb; i += BS) dacc += (double)partials[i];
    #pragma unroll
    for (int off = 32; off > 0; off >>= 1) dacc += __shfl_down(dacc, off, 64);
    int lane = threadIdx.x & 63, w = threadIdx.x >> 6;
    if (lane == 0) dsm[w] = dacc;
    __syncthreads();
    if (threadIdx.x == 0) {
        double tot = dsm[0] + dsm[1] + dsm[2] + dsm[3];
        c_sh = (float)(0.01 * 0.2 * tot / ((double)P * 15.0));
    }
    __syncthreads();
    float c = c_sh;

    long long stride = (long long)gridDim.x * blockDim.x;
    for (long long i = (long long)blockIdx.x * blockDim.x + threadIdx.x; i < n; i += stride) {
        const float4 O = *reinterpret_cast<const float4*>(outputs + i * 4);
        const float4 D = *reinterpret_cast<const float4*>(targets + i * 8 + 4);
        float s = 0.f;
        {
            float d = O.x - D.x, ad = fabsf(d);
            s += (ad < 1.f) ? 0.5f * d * d : ad - 0.5f;
        }
        {
            float d = O.y - D.y, ad = fabsf(d);
            s += (ad < 1.f) ? 0.5f * d * d : ad - 0.5f;
        }
        {
            float d = O.z - D.z, ad = fabsf(d);
            s += (ad < 1.f) ? 0.5f * d * d : ad - 0.5f;
        }
        {
            float d = O.w - D.w, ad = fabsf(d);
            s += (ad < 1.f) ? 0.5f * d * d : ad - 0.5f;
        }
        out[i] = 0.99f * s * inv_p + c;
    }
}

extern "C" void kernel_launch(void* const* d_in, const int* in_sizes, int n_in,
                              void* d_out, int out_size, void* d_ws, size_t ws_size,
                              hipStream_t stream) {
    const float* outputs = (const float*)d_in[0];
    const float* targets = (const float*)d_in[1];
    float* out = (float*)d_out;
    float* partials = (float*)d_ws;

    const int T = 16, F_DIR = 15;
    int P  = in_sizes[0] / (T * 4);          // 200000
    int n1 = F_DIR * P;                      // 3,000,000
    int n3 = out_size;                       // 16 * P

    int nb1 = (n1 + 4 * BS - 1) / (4 * BS);  // 2930 blocks, 4 items/thread
    dir_partials<<<nb1, BS, 0, stream>>>(outputs, targets, partials, n1, P);

    int nb3 = (n3 + BS - 1) / BS;
    if (nb3 > 2048) nb3 = 2048;
    out_kernel<<<nb3, BS, 0, stream>>>(outputs, targets, partials, nb1, out, n3, P, 1.0f / (float)P);
}

// Round 11
// 44.509 us; speedup vs baseline: 1.6976x; 1.6976x over previous
//
#include <hip/hip_runtime.h>

#define BS 256

__device__ __forceinline__ float fast_acos(float x) {
    // Abramowitz & Stegun 4.4.45, branchless; |err| <= ~6.8e-5 rad.
    float ax = fabsf(x);
    float s  = sqrtf(fmaxf(0.f, 1.f - ax));
    float p  = fmaf(ax, fmaf(ax, fmaf(ax, -0.0187293f, 0.0742610f), -0.2121144f), 1.5707288f);
    float r  = s * p;
    return (x >= 0.f) ? r : 3.14159265358979f - r;
}

__device__ __forceinline__ float dir_item(float4 L, float4 O, float4 Tn, bool first) {
    // pred_c = conv_bbox(last + outputs[t])
    float pa = L.x + O.x, pb = L.y + O.y, pc = L.z + O.z, pd = L.w + O.w;
    float Px0 = pa - 0.5f * pc, Py0 = pb - 0.5f * pd, Px1 = pa, Py1 = pb;
    // true_c = conv_bbox(targets[t+1])
    float Tx0 = Tn.x - 0.5f * Tn.z, Ty0 = Tn.y - 0.5f * Tn.w, Tx1 = Tn.x, Ty1 = Tn.y;
    // last_eff: frame 0 -> conv once; frames >=1 -> conv twice (collapsed)
    float Lx1 = L.x - 0.5f * L.z, Ly1 = L.y - 0.5f * L.w;      // conv once
    float Lx0, Ly0;
    if (first) { Lx0 = Lx1; Ly0 = Ly1; Lx1 = L.x; Ly1 = L.y; }
    else       { Lx0 = 0.5f * (L.x - L.z); Ly0 = 0.5f * (L.y - L.w); }

    float lxs[5] = {0.5f * (Lx0 + Lx1), Lx0, Lx0, Lx1, Lx1};
    float lys[5] = {0.5f * (Ly0 + Ly1), Ly0, Ly1, Ly0, Ly1};
    float pxs[5] = {0.5f * (Px0 + Px1), Px0, Px0, Px1, Px1};
    float pys[5] = {0.5f * (Py0 + Py1), Py0, Py1, Py0, Py1};
    float txs[5] = {0.5f * (Tx0 + Tx1), Tx0, Tx0, Tx1, Tx1};
    float tys[5] = {0.5f * (Ty0 + Ty1), Ty0, Ty1, Ty0, Ty1};

    float acc = 0.f;
    #pragma unroll
    for (int k = 0; k < 5; ++k) {
        float pdx = pxs[k] - lxs[k], pdy = pys[k] - lys[k];
        float tdx = txs[k] - lxs[k], tdy = tys[k] - lys[k];
        float p2  = pdx * pdx + pdy * pdy;
        float t2  = tdx * tdx + tdy * tdy;
        float dot = pdx * tdx + pdy * tdy;
        float inv = rsqrtf(p2 * t2);   // ref's +1e-6 eps shifts cos by <=1e-5: within budget
        float cosang = fminf(1.0f, fmaxf(-1.0f, dot * inv));
        acc += fast_acos(cosang);
    }
    return acc;
}

__device__ __forceinline__ float sl1_4(float4 O, float4 D) {
    float s = 0.f;
    { float d = O.x - D.x, ad = fabsf(d); s += (ad < 1.f) ? 0.5f * d * d : ad - 0.5f; }
    { float d = O.y - D.y, ad = fabsf(d); s += (ad < 1.f) ? 0.5f * d * d : ad - 0.5f; }
    { float d = O.z - D.z, ad = fabsf(d); s += (ad < 1.f) ? 0.5f * d * d : ad - 0.5f; }
    { float d = O.w - D.w, ad = fabsf(d); s += (ad < 1.f) ? 0.5f * d * d : ad - 0.5f; }
    return s;
}

// One thread owns one p for an 8-frame t-range (half 0: t=0..7, half 1: t=8..15).
// Each 32B targets record is loaded once; row t+1 comes from next iteration's
// registers (rotation), so every HBM line is fully consumed exactly once.
__global__ __launch_bounds__(BS) void fused_kernel(const float* __restrict__ outputs,
                                                   const float* __restrict__ targets,
                                                   float* __restrict__ out,
                                                   float* __restrict__ partials,
                                                   int P, float w) {
    __shared__ float smem[BS / 64];
    long long g = (long long)blockIdx.x * BS + threadIdx.x;
    float acc = 0.f;
    if (g < 2ll * P) {
        int half   = (g >= P) ? 1 : 0;
        long long p = g - (long long)half * P;
        int t_lo   = half ? 8 : 0;
        const float* trow = targets + ((long long)t_lo * P + p) * 8;
        const float* orow = outputs + ((long long)t_lo * P + p) * 4;
        float*       wrow = out + (long long)t_lo * P + p;
        const long long tstep = 8ll * P, ostep = 4ll * P;

        float4 Tf = *reinterpret_cast<const float4*>(trow);       // targets[t,p,0:4]
        float4 Ts = *reinterpret_cast<const float4*>(trow + 4);   // targets[t,p,4:8]
        float4 Ot = *reinterpret_cast<const float4*>(orow);       // outputs[t,p,:]

        #pragma unroll
        for (int it = 0; it < 8; ++it) {
            bool iterN = it < 7;            // full next iteration exists (uniform)
            bool needN = iterN || !half;    // next row's first half needed for dir
            float4 Tnf, Tns, On;
            if (needN) Tnf = *reinterpret_cast<const float4*>(trow + tstep);
            if (iterN) {
                Tns = *reinterpret_cast<const float4*>(trow + tstep + 4);
                On  = *reinterpret_cast<const float4*>(orow + ostep);
            }
            // smooth-L1 part for frame t (second kernel adds the dir constant)
            wrow[0] = sl1_4(Ot, Ts) * w;
            if (needN) acc += dir_item(Tf, Ot, Tnf, (!half) && (it == 0));
            Tf = Tnf; Ts = Tns; Ot = On;
            trow += tstep; orow += ostep; wrow += P;
        }
    }
    #pragma unroll
    for (int off = 32; off > 0; off >>= 1) acc += __shfl_down(acc, off, 64);
    int lane = threadIdx.x & 63, w64 = threadIdx.x >> 6;
    if (lane == 0) smem[w64] = acc;
    __syncthreads();
    if (threadIdx.x == 0) {
        float r = 0.f;
        #pragma unroll
        for (int i = 0; i < BS / 64; ++i) r += smem[i];
        partials[blockIdx.x] = r;
    }
}

__global__ void finalize_kernel(const float* __restrict__ partials, int nb,
                                float* __restrict__ out, long long n4, int P) {
    __shared__ double dsm[BS / 64];
    __shared__ float c_sh;
    double dacc = 0.0;
    for (int i = threadIdx.x; i < nb; i += BS) dacc += (double)partials[i];
    #pragma unroll
    for (int off = 32; off > 0; off >>= 1) dacc += __shfl_down(dacc, off, 64);
    int lane = threadIdx.x & 63, w = threadIdx.x >> 6;
    if (lane == 0) dsm[w] = dacc;
    __syncthreads();
    if (threadIdx.x == 0) {
        double tot = dsm[0] + dsm[1] + dsm[2] + dsm[3];
        c_sh = (float)(0.01 * 0.2 * tot / ((double)P * 15.0));
    }
    __syncthreads();
    float c = c_sh;

    float4* o4 = reinterpret_cast<float4*>(out);
    long long stride = (long long)gridDim.x * blockDim.x;
    for (long long i = (long long)blockIdx.x * blockDim.x + threadIdx.x; i < n4; i += stride) {
        float4 v = o4[i];
        v.x += c; v.y += c; v.z += c; v.w += c;
        o4[i] = v;
    }
}

extern "C" void kernel_launch(void* const* d_in, const int* in_sizes, int n_in,
                              void* d_out, int out_size, void* d_ws, size_t ws_size,
                              hipStream_t stream) {
    const float* outputs = (const float*)d_in[0];
    const float* targets = (const float*)d_in[1];
    float* out = (float*)d_out;
    float* partials = (float*)d_ws;

    const int T = 16;
    int P = in_sizes[0] / (T * 4);                 // 200000

    long long nthreads = 2ll * P;                  // one per (p, t-half)
    int nb1 = (int)((nthreads + BS - 1) / BS);     // 1563 blocks, all co-resident
    fused_kernel<<<nb1, BS, 0, stream>>>(outputs, targets, out, partials,
                                         P, 0.99f / (float)P);

    long long n4 = (long long)out_size / 4;        // out_size = 16P, divisible by 4
    int nb2 = (int)((n4 + BS - 1) / BS);
    if (nb2 > 2048) nb2 = 2048;
    finalize_kernel<<<nb2, BS, 0, stream>>>(partials, nb1, out, n4, P);
}